// Round 1
// 1074.980 us; speedup vs baseline: 2.6903x; 2.6903x over previous
//
#include <hip/hip_runtime.h>
#include <hip/hip_bf16.h>
#include <math.h>

#define BATCH 256
#define DIM 1024
#define KG 7
#define VOCAB 32000

typedef unsigned short u16;
typedef unsigned int u32;
typedef __attribute__((ext_vector_type(8))) short short8v;
typedef __attribute__((ext_vector_type(4))) float f32x4;

__device__ __forceinline__ int iclamp(int v, int lo, int hi) { return v < lo ? lo : (v > hi ? hi : v); }

__device__ __forceinline__ u16 f2bf(float f) {
    union { float f; u32 u; } x; x.f = f;
    u32 r = x.u + 0x7FFFu + ((x.u >> 16) & 1u);   // round-to-nearest-even
    return (u16)(r >> 16);
}
__device__ __forceinline__ float bf2f(u16 b) {
    union { u32 u; float f; } x; x.u = ((u32)b) << 16;
    return x.f;
}

// ---------------- block reduce (256 threads, 4 waves) ----------------
__device__ __forceinline__ float block_reduce(float v, float* sm) {
    #pragma unroll
    for (int o = 32; o > 0; o >>= 1) v += __shfl_down(v, o, 64);
    int wid = threadIdx.x >> 6, lane = threadIdx.x & 63;
    if (lane == 0) sm[wid] = v;
    __syncthreads();
    if (threadIdx.x == 0) sm[0] = sm[0] + sm[1] + sm[2] + sm[3];
    __syncthreads();
    float r = sm[0];
    __syncthreads();
    return r;
}

// ---------------- addr row inverse norms ----------------
__global__ void addr_norm_k(const float* __restrict__ addr, float* __restrict__ addr_inv) {
    __shared__ float sm[4];
    for (int k = 0; k < KG; k++) {
        float s = 0.f;
        for (int d = threadIdx.x; d < DIM; d += 256) { float a = addr[k * DIM + d]; s += a * a; }
        float tot = block_reduce(s, sm);
        if (threadIdx.x == 0) addr_inv[k] = 1.0f / fmaxf(sqrtf(tot), 1e-12f);
        __syncthreads();
    }
}

// ---------------- per-sample: f_emb, xcat(h,f), scores->pi, idx, gamma ----------------
__global__ void sample_k(const float* __restrict__ h, const float* __restrict__ fib_s,
                         const float* __restrict__ fib_e, const int* __restrict__ tok,
                         const float* __restrict__ opemb, const float* __restrict__ num_w,
                         const float* __restrict__ num_b, const float* __restrict__ addr,
                         const float* __restrict__ fs_w, const float* __restrict__ fs_b,
                         const float* __restrict__ fe_w, const float* __restrict__ fe_b,
                         const float* __restrict__ c1w, const float* __restrict__ c1b,
                         const float* __restrict__ c2w, const float* __restrict__ c2b,
                         const float* __restrict__ addr_inv, float* __restrict__ xcat,
                         float* __restrict__ gamma_ws, int* __restrict__ kidx,
                         float* __restrict__ pi_out) {
    int b = blockIdx.x;
    int t = tok[b];
    bool ctrl = (t < 7);
    int tcl = iclamp(t, 0, 6);
    float numv = (float)t - 7.0f;
    float fsv = fib_s[b], fev = fib_e[b];
    float vv = 0.f, dot[KG];
    #pragma unroll
    for (int k = 0; k < KG; k++) dot[k] = 0.f;
    for (int d = threadIdx.x; d < DIM; d += 256) {
        float femb = tanhf(fsv * fs_w[d] + fs_b[d] + fev * fe_w[d] + fe_b[d]);
        float hf = h[b * DIM + d];
        xcat[b * 2048 + d] = hf;
        xcat[b * 2048 + DIM + d] = femb;
        float v;
        if (ctrl) v = opemb[tcl * DIM + d];
        else      v = numv * num_w[d] + num_b[d] + femb;
        vv += v * v;
        #pragma unroll
        for (int k = 0; k < KG; k++) dot[k] += v * addr[k * DIM + d];
    }
    __shared__ float sm[4];
    vv = block_reduce(vv, sm);
    float sc[KG];
    for (int k = 0; k < KG; k++) sc[k] = block_reduce(dot[k], sm);
    if (threadIdx.x == 0) {
        float inv_v = 1.0f / fmaxf(sqrtf(vv), 1e-12f);
        float m = -1e30f;
        for (int k = 0; k < KG; k++) { sc[k] = 5.0f * sc[k] * inv_v * addr_inv[k]; m = fmaxf(m, sc[k]); }
        float se = 0.f, p[KG];
        for (int k = 0; k < KG; k++) { p[k] = expf(sc[k] - m); se += p[k]; }
        float ent = 0.f, best = -1.f;
        int idx = 0;
        for (int k = 0; k < KG; k++) {
            p[k] /= se;
            ent -= p[k] * logf(p[k] + 1e-8f);
            if (p[k] > best) { best = p[k]; idx = k; }
        }
        float acc = c2b[0];
        for (int j = 0; j < 16; j++) {
            float x = fmaxf(0.0f, ent * c1w[j * 2 + 0] + c1b[j]);
            acc += x * c2w[j];
        }
        float g = (acc > 20.f) ? acc : log1pf(expf(acc));  // softplus
        gamma_ws[b] = g;
        kidx[b] = idx;
        for (int k = 0; k < KG; k++) pi_out[b * KG + k] = p[k];
    }
}

// ---------------- group samples by expert, build 16-row tiles ----------------
__global__ void group_k(const int* __restrict__ kidx, int* __restrict__ order,
                        int* __restrict__ tile_k, int* __restrict__ tile_r0,
                        int* __restrict__ tile_nr, int* __restrict__ ntiles) {
    __shared__ int kk[BATCH];
    __shared__ int cnt[KG];
    __shared__ int base_s[KG];
    int tid = threadIdx.x;
    kk[tid] = iclamp(kidx[tid], 0, 6);
    __syncthreads();
    if (tid < KG) { int c = 0; for (int i = 0; i < BATCH; i++) c += (kk[i] == tid); cnt[tid] = c; }
    __syncthreads();
    if (tid == 0) { int s = 0; for (int k = 0; k < KG; k++) { base_s[k] = s; s += cnt[k]; } }
    __syncthreads();
    int mk = kk[tid];
    int rank = 0;
    for (int i = 0; i < tid; i++) rank += (kk[i] == mk);
    order[base_s[mk] + rank] = tid;
    if (tid == 0) {
        int nt = 0;
        for (int k = 0; k < KG; k++)
            for (int off = 0; off < cnt[k]; off += 16) {
                tile_k[nt] = k; tile_r0[nt] = base_s[k] + off; tile_nr[nt] = min(16, cnt[k] - off); nt++;
            }
        *ntiles = nt;
    }
}

// ---------------- one-time: transpose+convert W[k][d][e] -> Wt[k][e][d] bf16 ----------------
__global__ __launch_bounds__(256) void convt_k(const float* __restrict__ W, u16* __restrict__ Wt) {
    int kg = blockIdx.z;
    int d0 = blockIdx.x * 64;
    int e0 = blockIdx.y * 64;
    __shared__ float T[64][68];
    int tid = threadIdx.x;
    {
        int i = tid >> 2;            // d row 0..63
        int j4 = (tid & 3) * 16;     // e chunk
        const float* src = W + (size_t)kg * 1048576 + (size_t)(d0 + i) * 1024 + e0 + j4;
        #pragma unroll
        for (int j = 0; j < 4; j++) {
            float4 v = *reinterpret_cast<const float4*>(src + j * 4);
            *reinterpret_cast<float4*>(&T[i][j4 + j * 4]) = v;
        }
    }
    __syncthreads();
    {
        int e = tid >> 2;            // e row 0..63
        int d4 = (tid & 3) * 16;     // d chunk
        u16 tmp[16];
        #pragma unroll
        for (int x = 0; x < 16; x++) tmp[x] = f2bf(T[d4 + x][e]);
        u16* dst = Wt + (size_t)kg * 1048576 + (size_t)(e0 + e) * 1024 + d0 + d4;
        *reinterpret_cast<short8v*>(dst) = *reinterpret_cast<short8v*>(tmp);
        *reinterpret_cast<short8v*>(dst + 8) = *reinterpret_cast<short8v*>(tmp + 8);
    }
}

// ---------------- fp32 grouped GEMM (kept for the one-time U/V -> c computation) ----------------
__global__ __launch_bounds__(256) void gg_k(const float* __restrict__ Abuf, int lda,
                                            const float* __restrict__ Bbase,
                                            const float* __restrict__ Cadd,
                                            float* __restrict__ outz, int act,
                                            const int* __restrict__ order,
                                            const int* __restrict__ tile_k,
                                            const int* __restrict__ tile_r0,
                                            const int* __restrict__ tile_nr,
                                            const int* __restrict__ ntiles) {
    int t = blockIdx.y;
    int nt = iclamp(*ntiles, 0, 22);
    if (t >= nt) return;
    int kg = iclamp(tile_k[t], 0, 6);
    int nr = iclamp(tile_nr[t], 1, 16);
    int r0 = iclamp(tile_r0[t], 0, 255);
    int n0 = blockIdx.x * 128;
    __shared__ int rows[16];
    __shared__ float As[16][33];
    __shared__ float Bs[32][128];
    int tid = threadIdx.x;
    if (tid < 16) {
        int ro = iclamp(r0 + min(tid, nr - 1), 0, 255);
        rows[tid] = iclamp(order[ro], 0, 255);
    }
    __syncthreads();
    const float* Bmat = Bbase + (size_t)kg * DIM * DIM;
    float acc[2][4] = {};
    int tr = tid >> 5;
    int tc = tid & 31;
    for (int k0 = 0; k0 < DIM; k0 += 32) {
        {
            int e = tid;
            #pragma unroll
            for (int rep = 0; rep < 2; rep++) {
                int i = e >> 5, kx = e & 31;
                As[i][kx] = Abuf[(size_t)rows[i] * lda + k0 + kx];
                e += 256;
            }
        }
        {
            #pragma unroll
            for (int rep = 0; rep < 16; rep++) {
                int e = tid + rep * 256;
                int dd = e >> 7, cc = e & 127;
                Bs[dd][cc] = Bmat[(size_t)(k0 + dd) * DIM + n0 + cc];
            }
        }
        __syncthreads();
        #pragma unroll
        for (int kx = 0; kx < 32; kx++) {
            float a0 = As[tr][kx], a1 = As[tr + 8][kx];
            float b0 = Bs[kx][tc], b1 = Bs[kx][tc + 32], b2v = Bs[kx][tc + 64], b3 = Bs[kx][tc + 96];
            acc[0][0] += a0 * b0; acc[0][1] += a0 * b1; acc[0][2] += a0 * b2v; acc[0][3] += a0 * b3;
            acc[1][0] += a1 * b0; acc[1][1] += a1 * b1; acc[1][2] += a1 * b2v; acc[1][3] += a1 * b3;
        }
        __syncthreads();
    }
    #pragma unroll
    for (int ii = 0; ii < 2; ii++) {
        int i = tr + ii * 8;
        if (i < nr) {
            int r = rows[i];
            #pragma unroll
            for (int j = 0; j < 4; j++) {
                int c = n0 + tc + j * 32;
                float v = acc[ii][j];
                if (Cadd) v += Cadd[(size_t)r * DIM + c];
                if (act == 1) v = tanhf(v);
                outz[(size_t)r * DIM + c] = v;
            }
        }
    }
}

// ---------------- MFMA bf16 grouped GEMM for the DEQ loop ----------------
// z'[r][e] = tanh( sum_d z[r][d]*W[k][d][e] + c[r][e] ), z bf16, Wt = W transposed bf16 [k][e][d]
// tile: 16 rows x 64 cols, 4 waves, each wave one 16x16 mfma frag over K, K-chunk 64 double-buffered.
__global__ __launch_bounds__(256) void ggm_k(const u16* __restrict__ zin,
                                             const u16* __restrict__ Wt,
                                             const float* __restrict__ c_buf,
                                             u16* __restrict__ zout,
                                             const int* __restrict__ order,
                                             const int* __restrict__ tile_k,
                                             const int* __restrict__ tile_r0,
                                             const int* __restrict__ tile_nr,
                                             const int* __restrict__ ntiles) {
    int t = blockIdx.y;
    int nt = iclamp(*ntiles, 0, 22);
    if (t >= nt) return;
    int kg = iclamp(tile_k[t], 0, 6);
    int nr = iclamp(tile_nr[t], 1, 16);
    int r0 = iclamp(tile_r0[t], 0, 255);
    int c0 = blockIdx.x * 64;
    __shared__ int rows[16];
    __shared__ __align__(16) u16 Al[16 * 1032];      // A rows padded +8 u16 -> 129 16B-chunks/row (conflict-free frag reads)
    __shared__ __align__(16) u16 Bl[2 * 64 * 72];    // B rows padded 64->72 u16 -> 9 chunks/row (conflict-free frag reads)
    int tid = threadIdx.x;
    if (tid < 16) {
        int ro = iclamp(r0 + min(tid, nr - 1), 0, 255);
        rows[tid] = iclamp(order[ro], 0, 255);
    }
    __syncthreads();
    // stage A (16 z rows, 2KB each) into LDS
    {
        int r = tid >> 4, ch = tid & 15;
        const u16* src = zin + (size_t)rows[r] * 1024 + ch * 64;
        u16* dst = Al + r * 1032 + ch * 64;
        #pragma unroll
        for (int i = 0; i < 8; i++)
            *reinterpret_cast<short8v*>(dst + i * 8) = *reinterpret_cast<const short8v*>(src + i * 8);
    }
    const u16* Wb = Wt + (size_t)kg * 1048576;
    // stage B chunk 0 directly; prefetch chunk 1 into regs
    short8v breg[2];
    {
        #pragma unroll
        for (int j = 0; j < 2; j++) {
            int ch = tid + 256 * j; int e = ch >> 3, k16 = ch & 7;
            short8v v = *reinterpret_cast<const short8v*>(Wb + (size_t)(c0 + e) * 1024 + k16 * 8);
            *reinterpret_cast<short8v*>(Bl + e * 72 + k16 * 8) = v;
        }
        #pragma unroll
        for (int j = 0; j < 2; j++) {
            int ch = tid + 256 * j; int e = ch >> 3, k16 = ch & 7;
            breg[j] = *reinterpret_cast<const short8v*>(Wb + (size_t)(c0 + e) * 1024 + 64 + k16 * 8);
        }
    }
    int w = tid >> 6, l = tid & 63;
    int apart = l >> 4;
    const u16* Abase = Al + (l & 15) * 1032 + apart * 8;
    int e_loc = w * 16 + (l & 15);
    f32x4 acc = {0.f, 0.f, 0.f, 0.f};
    for (int s = 0; s < 16; s++) {
        __syncthreads();   // B chunk s visible; compute of s-1 done (buffer (s+1)&1 free)
        if (s + 1 < 16) {
            #pragma unroll
            for (int j = 0; j < 2; j++) {
                int ch = tid + 256 * j; int e = ch >> 3, k16 = ch & 7;
                *reinterpret_cast<short8v*>(Bl + ((s + 1) & 1) * 4608 + e * 72 + k16 * 8) = breg[j];
            }
            if (s + 2 < 16) {
                #pragma unroll
                for (int j = 0; j < 2; j++) {
                    int ch = tid + 256 * j; int e = ch >> 3, k16 = ch & 7;
                    breg[j] = *reinterpret_cast<const short8v*>(Wb + (size_t)(c0 + e) * 1024 + (s + 2) * 64 + k16 * 8);
                }
            }
        }
        const u16* Ab = Abase + s * 64;
        const u16* Bb = Bl + (s & 1) * 4608 + e_loc * 72 + apart * 8;
        short8v av0 = *reinterpret_cast<const short8v*>(Ab);
        short8v av1 = *reinterpret_cast<const short8v*>(Ab + 32);
        short8v bv0 = *reinterpret_cast<const short8v*>(Bb);
        short8v bv1 = *reinterpret_cast<const short8v*>(Bb + 32);
        acc = __builtin_amdgcn_mfma_f32_16x16x32_bf16(av0, bv0, acc, 0, 0, 0);
        acc = __builtin_amdgcn_mfma_f32_16x16x32_bf16(av1, bv1, acc, 0, 0, 0);
    }
    // epilogue: C/D layout col = lane&15, row = (lane>>4)*4 + reg  [m89-verified]
    int col = c0 + e_loc;
    #pragma unroll
    for (int r = 0; r < 4; r++) {
        int rl = apart * 4 + r;
        if (rl < nr) {
            int pr = rows[rl];
            float v = acc[r] + c_buf[(size_t)pr * 1024 + col];
            v = tanhf(v);
            zout[(size_t)pr * 1024 + col] = f2bf(v);
        }
    }
}

// ---------------- fp32 linear, 16x128 tile (kept for stab1/stab2) ----------------
__global__ __launch_bounds__(256) void lin_k(const float* __restrict__ Abuf, int lda,
                                             const float* __restrict__ Wt, int Kdim,
                                             const float* __restrict__ bias,
                                             float* __restrict__ out_f,
                                             int N, int act) {
    int n0 = blockIdx.x * 128;
    int m0 = blockIdx.y * 16;
    __shared__ float As[16][33];
    __shared__ float Bs[32][129];
    int tid = threadIdx.x;
    int tr = tid >> 5, tc = tid & 31;
    float acc[2][4] = {};
    for (int k0 = 0; k0 < Kdim; k0 += 32) {
        {
            int e = tid;
            #pragma unroll
            for (int rep = 0; rep < 2; rep++) {
                int i = e >> 5, kx = e & 31;
                As[i][kx] = Abuf[(size_t)(m0 + i) * lda + k0 + kx];
                e += 256;
            }
        }
        {
            #pragma unroll
            for (int rep = 0; rep < 16; rep++) {
                int e = tid + rep * 256;
                int o = e >> 5, ix = e & 31;
                Bs[ix][o] = Wt[(size_t)(n0 + o) * Kdim + k0 + ix];
            }
        }
        __syncthreads();
        #pragma unroll
        for (int kx = 0; kx < 32; kx++) {
            float a0 = As[tr][kx], a1 = As[tr + 8][kx];
            float b0 = Bs[kx][tc], b1 = Bs[kx][tc + 32], b2v = Bs[kx][tc + 64], b3 = Bs[kx][tc + 96];
            acc[0][0] += a0 * b0; acc[0][1] += a0 * b1; acc[0][2] += a0 * b2v; acc[0][3] += a0 * b3;
            acc[1][0] += a1 * b0; acc[1][1] += a1 * b1; acc[1][2] += a1 * b2v; acc[1][3] += a1 * b3;
        }
        __syncthreads();
    }
    #pragma unroll
    for (int ii = 0; ii < 2; ii++) {
        int m = m0 + tr + ii * 8;
        #pragma unroll
        for (int j = 0; j < 4; j++) {
            int n = n0 + tc + j * 32;
            float v = acc[ii][j] + bias[n];
            if (act == 1) v = tanhf(v);
            else if (act == 2) v = 1.0f / (1.0f + expf(-v));
            out_f[(size_t)m * N + n] = v;
        }
    }
}

// ---------------- fp32 linear, 64x256 tile, 8x8 register blocking (decoder) ----------------
__global__ __launch_bounds__(256) void lin2_k(const float* __restrict__ A, int lda,
                                              const float* __restrict__ Wt, int Kdim,
                                              const float* __restrict__ bias,
                                              float* __restrict__ out_f,
                                              int N, int act) {
    int n0 = blockIdx.x * 256;
    int m0 = blockIdx.y * 64;
    __shared__ float As[16][68];
    __shared__ float Bs[16][260];
    int tid = threadIdx.x;
    int rg = tid >> 5, cg = tid & 31;
    float acc[8][8] = {};
    for (int k0 = 0; k0 < Kdim; k0 += 16) {
        {
            int m = tid & 63, kq = tid >> 6;
            float4 v = *reinterpret_cast<const float4*>(A + (size_t)(m0 + m) * lda + k0 + kq * 4);
            As[kq * 4 + 0][m] = v.x; As[kq * 4 + 1][m] = v.y;
            As[kq * 4 + 2][m] = v.z; As[kq * 4 + 3][m] = v.w;
        }
        {
            const float* wp = Wt + (size_t)(n0 + tid) * Kdim + k0;
            #pragma unroll
            for (int j = 0; j < 4; j++) {
                float4 v = *reinterpret_cast<const float4*>(wp + j * 4);
                Bs[j * 4 + 0][tid] = v.x; Bs[j * 4 + 1][tid] = v.y;
                Bs[j * 4 + 2][tid] = v.z; Bs[j * 4 + 3][tid] = v.w;
            }
        }
        __syncthreads();
        #pragma unroll
        for (int kx = 0; kx < 16; kx++) {
            float a[8], b[8];
            *reinterpret_cast<float4*>(a)     = *reinterpret_cast<const float4*>(&As[kx][rg * 8]);
            *reinterpret_cast<float4*>(a + 4) = *reinterpret_cast<const float4*>(&As[kx][rg * 8 + 4]);
            *reinterpret_cast<float4*>(b)     = *reinterpret_cast<const float4*>(&Bs[kx][cg * 8]);
            *reinterpret_cast<float4*>(b + 4) = *reinterpret_cast<const float4*>(&Bs[kx][cg * 8 + 4]);
            #pragma unroll
            for (int i = 0; i < 8; i++)
                #pragma unroll
                for (int j = 0; j < 8; j++)
                    acc[i][j] += a[i] * b[j];
        }
        __syncthreads();
    }
    #pragma unroll
    for (int i = 0; i < 8; i++) {
        int m = m0 + rg * 8 + i;
        float o[8];
        #pragma unroll
        for (int j = 0; j < 8; j++) {
            int n = n0 + cg * 8 + j;
            float v = acc[i][j] + bias[n];
            if (act == 1) v = tanhf(v);
            else if (act == 2) v = 1.0f / (1.0f + expf(-v));
            o[j] = v;
        }
        float* op = out_f + (size_t)m * N + n0 + cg * 8;
        *reinterpret_cast<float4*>(op)     = *reinterpret_cast<const float4*>(o);
        *reinterpret_cast<float4*>(op + 4) = *reinterpret_cast<const float4*>(o + 4);
    }
}

// ---------------- small elementwise ----------------
__global__ void init_z_k(const float* __restrict__ c, u16* __restrict__ z) {
    int i = blockIdx.x * 256 + threadIdx.x;
    z[i] = f2bf(tanhf(c[i]));
}

__global__ void hnext_k(const float* __restrict__ xcat, const float* __restrict__ alocal,
                        const u16* __restrict__ zfin, const float* __restrict__ gamma_ws,
                        float* __restrict__ out_h) {
    int i = blockIdx.x * 256 + threadIdx.x;
    int b = i >> 10, d = i & 1023;
    out_h[i] = xcat[b * 2048 + d] + gamma_ws[b] * alocal[i] * bf2f(zfin[i]);
}

extern "C" void kernel_launch(void* const* d_in, const int* in_sizes, int n_in,
                              void* d_out, int out_size, void* d_ws, size_t ws_size,
                              hipStream_t stream) {
    const float* h     = (const float*)d_in[0];
    const float* fib_s = (const float*)d_in[1];
    const float* fib_e = (const float*)d_in[2];
    const int*   tok   = (const int*)d_in[3];
    const float* opemb = (const float*)d_in[4];
    const float* num_w = (const float*)d_in[5];
    const float* num_b = (const float*)d_in[6];
    const float* addr  = (const float*)d_in[7];
    const float* Wm    = (const float*)d_in[8];
    const float* Um    = (const float*)d_in[9];
    const float* Vm    = (const float*)d_in[10];
    const float* fs_w  = (const float*)d_in[11];
    const float* fs_b  = (const float*)d_in[12];
    const float* fe_w  = (const float*)d_in[13];
    const float* fe_b  = (const float*)d_in[14];
    const float* s1w   = (const float*)d_in[15];
    const float* s1b   = (const float*)d_in[16];
    const float* s2w   = (const float*)d_in[17];
    const float* s2b   = (const float*)d_in[18];
    const float* c1w   = (const float*)d_in[19];
    const float* c1b   = (const float*)d_in[20];
    const float* c2w   = (const float*)d_in[21];
    const float* c2b   = (const float*)d_in[22];
    const float* dec_w = (const float*)d_in[23];
    const float* dec_b = (const float*)d_in[24];

    float* out_h      = (float*)d_out;
    float* out_logits = out_h + BATCH * DIM;                 // element 262144
    float* out_pi     = out_h + BATCH * DIM + BATCH * VOCAB; // element 8454144

    // ALL scratch lives in the logits region (8,192,000 floats = 32.77 MB).
    // Everything is write-before-read; the decoder GEMM overwrites it at the end.
    float* scr      = out_logits;
    float* xcat     = scr;                   // 256 x 2048 (h | f_emb)           [0 .. 524288)
    float* c_buf    = scr + 524288;          // 256 x 1024                       [524288 .. 786432)
    float* stab_h   = scr + 786432;          // 256 x 1024
    float* alocal   = scr + 1048576;         // 256 x 1024
    float* addr_inv = scr + 1310720;         // 8
    float* gamma_ws = scr + 1310728;         // 256
    int* kidx    = (int*)(scr + 1310984);    // 256
    int* order   = (int*)(scr + 1311240);    // 256
    int* tile_k  = (int*)(scr + 1311496);    // 32
    int* tile_r0 = (int*)(scr + 1311528);    // 32
    int* tile_nr = (int*)(scr + 1311560);    // 32
    int* ntiles  = (int*)(scr + 1311592);    // 1
    u16* za      = (u16*)(scr + 1311616);    // 256x1024 bf16 (131072 floats)
    u16* zb      = (u16*)(scr + 1442688);    // 256x1024 bf16
    u16* Wt      = (u16*)(scr + 1573760);    // 7x1024x1024 bf16 (3670016 floats) ends 5243776 < 8192000

    addr_norm_k<<<1, 256, 0, stream>>>(addr, addr_inv);
    sample_k<<<BATCH, 256, 0, stream>>>(h, fib_s, fib_e, tok, opemb, num_w, num_b, addr,
                                        fs_w, fs_b, fe_w, fe_b, c1w, c1b, c2w, c2b,
                                        addr_inv, xcat, gamma_ws, kidx, out_pi);
    group_k<<<1, 256, 0, stream>>>(kidx, order, tile_k, tile_r0, tile_nr, ntiles);
    // one-time W -> Wt (bf16, transposed) for the MFMA DEQ loop
    convt_k<<<dim3(16, 16, KG), 256, 0, stream>>>(Wm, Wt);

    dim3 gg_grid(8, 22);
    // c = h @ U[k]  (fp32, one-time)
    gg_k<<<gg_grid, 256, 0, stream>>>(xcat, 2048, Um, nullptr, c_buf, 0,
                                      order, tile_k, tile_r0, tile_nr, ntiles);
    // c += f_emb @ V[k]
    gg_k<<<gg_grid, 256, 0, stream>>>(xcat + 1024, 2048, Vm, c_buf, c_buf, 0,
                                      order, tile_k, tile_r0, tile_nr, ntiles);
    // z1 = tanh(c)  (bf16)
    init_z_k<<<1024, 256, 0, stream>>>(c_buf, za);
    // 39 more applications -> f^40(0) via bf16 MFMA
    u16* zi = za;
    u16* zo = zb;
    dim3 ggm_grid(16, 22);
    for (int it = 0; it < 39; it++) {
        ggm_k<<<ggm_grid, 256, 0, stream>>>(zi, Wt, c_buf, zo,
                                            order, tile_k, tile_r0, tile_nr, ntiles);
        u16* tmp = zi; zi = zo; zo = tmp;
    }
    // stab path (fp32, unchanged)
    lin_k<<<dim3(8, 16), 256, 0, stream>>>(xcat, 2048, s1w, 2048, s1b, stab_h, DIM, 1);
    lin_k<<<dim3(8, 16), 256, 0, stream>>>(stab_h, 1024, s2w, 1024, s2b, alocal, DIM, 2);
    // h_next = h + gamma * alpha_local * z_star
    hnext_k<<<1024, 256, 0, stream>>>(xcat, alocal, zi, gamma_ws, out_h);
    // logits = h_next @ dec_w^T + dec_b (64x256 tile, 8x8 regs; overwrites scratch)
    lin2_k<<<dim3(125, 4), 256, 0, stream>>>(out_h, 1024, dec_w, 1024, dec_b,
                                             out_logits, VOCAB, 0);
}